// Round 1
// baseline (128.162 us; speedup 1.0000x reference)
//
#include <hip/hip_runtime.h>
#include <hip/hip_bf16.h>

#define B_   64
#define H_   1024
#define E_   512
#define V_   50000
#define S_   400
#define EXTV 50100        // V + 100
#define K2   2048         // 2H
#define KP   2560         // 2H + E
#define VP   50016        // padded e row stride (multiple of 16)
#define NBLK 782          // ceil(V / 64)
#define PSTR 800          // padded partial-sum stride

typedef float  f32x4  __attribute__((ext_vector_type(4)));
typedef __bf16 bf16x8 __attribute__((ext_vector_type(8)));

static __device__ __forceinline__ bf16x8 pack_bf16(f32x4 a, f32x4 b) {
    bf16x8 r;
    r[0] = (__bf16)a[0]; r[1] = (__bf16)a[1]; r[2] = (__bf16)a[2]; r[3] = (__bf16)a[3];
    r[4] = (__bf16)b[0]; r[5] = (__bf16)b[1]; r[6] = (__bf16)b[2]; r[7] = (__bf16)b[3];
    return r;
}

// ---------------- p_gen: 64 dots of length 2560 -----------------------------
__global__ __launch_bounds__(256) void k_pgen(const float* __restrict__ dec,
                                              const float* __restrict__ ctx,
                                              const float* __restrict__ emb,
                                              const float* __restrict__ Wp,
                                              const float* __restrict__ bp,
                                              float* __restrict__ pg,
                                              float* __restrict__ out1) {
    int b = blockIdx.x;
    int tid = threadIdx.x;
    float s = 0.f;
    for (int k = tid; k < KP; k += 256) {
        float x;
        if (k < H_)          x = dec[b * H_ + k];
        else if (k < 2 * H_) x = ctx[b * H_ + k - H_];
        else                 x = emb[b * E_ + k - 2 * H_];
        s += x * Wp[k];
    }
#pragma unroll
    for (int m = 32; m >= 1; m >>= 1) s += __shfl_xor(s, m);
    __shared__ float r[4];
    int wave = tid >> 6, lane = tid & 63;
    if (lane == 0) r[wave] = s;
    __syncthreads();
    if (tid == 0) {
        float t = r[0] + r[1] + r[2] + r[3] + bp[0];
        float p = 1.f / (1.f + __expf(-t));
        pg[b]   = p;
        out1[b] = p;
    }
}

// ---------------- mid GEMM (split-K partials): M=64, N=1024, K=2048 ---------
__global__ __launch_bounds__(256) void k_gemm_mid(const float* __restrict__ dec,
                                                  const float* __restrict__ ctx,
                                                  const float* __restrict__ Wm,
                                                  float* __restrict__ pmid) {
    int nt   = blockIdx.x;             // 0..15  (h-tile of 64)
    int kc   = blockIdx.y;             // 0..7   (K-chunk of 256)
    int wave = threadIdx.x >> 6;
    int lane = threadIdx.x & 63;
    int lr   = lane & 15, lg = lane >> 4;
    int col  = nt * 64 + wave * 16 + lr;          // h index
    const float* wrow = Wm + (size_t)col * K2;
    f32x4 acc[4] = {};
#pragma unroll
    for (int ks = 0; ks < 8; ++ks) {
        int k = kc * 256 + ks * 32 + lg * 8;
        const float* xb; int krel;
        if (k < H_) { xb = dec; krel = k; } else { xb = ctx; krel = k - H_; }
        f32x4 w0 = *(const f32x4*)(wrow + k);
        f32x4 w1 = *(const f32x4*)(wrow + k + 4);
        bf16x8 bf = pack_bf16(w0, w1);
#pragma unroll
        for (int mf = 0; mf < 4; ++mf) {
            const float* xp = xb + (size_t)(mf * 16 + lr) * H_ + krel;
            f32x4 a0 = *(const f32x4*)xp;
            f32x4 a1 = *(const f32x4*)(xp + 4);
            bf16x8 af = pack_bf16(a0, a1);
            acc[mf] = __builtin_amdgcn_mfma_f32_16x16x32_bf16(af, bf, acc[mf], 0, 0, 0);
        }
    }
#pragma unroll
    for (int mf = 0; mf < 4; ++mf)
#pragma unroll
        for (int r = 0; r < 4; ++r) {
            int row = mf * 16 + lg * 4 + r;       // batch index
            pmid[((size_t)kc * B_ + row) * H_ + col] = acc[mf][r];
        }
}

// ---------------- reduce split-K partials, bias, tanh, -> bf16 --------------
__global__ __launch_bounds__(256) void k_mid_reduce(const float* __restrict__ pmid,
                                                    const float* __restrict__ bm,
                                                    __bf16* __restrict__ midb) {
    int idx = blockIdx.x * 256 + threadIdx.x;     // 65536
    int m = idx >> 10, h = idx & (H_ - 1);
    float s = bm[h];
#pragma unroll
    for (int kc = 0; kc < 8; ++kc) s += pmid[((size_t)kc * B_ + m) * H_ + h];
    midb[idx] = (__bf16)tanhf(s);
    (void)m;
}

// ---------------- big GEMM: e = exp(clip(mid @ Wv^T + bv) - 50) -------------
__global__ __launch_bounds__(256) void k_gemm_vocab(const __bf16* __restrict__ midb,
                                                    const float* __restrict__ Wv,
                                                    const float* __restrict__ bv,
                                                    float* __restrict__ e,
                                                    float* __restrict__ psum) {
    int blk  = blockIdx.x;
    int wave = threadIdx.x >> 6;
    int lane = threadIdx.x & 63;
    int lr   = lane & 15, lg = lane >> 4;
    int col  = blk * 64 + wave * 16 + lr;         // vocab index
    bool valid = col < V_;
    int colc = valid ? col : V_ - 1;
    const float* wrow = Wv + (size_t)colc * H_;
    f32x4 acc[4] = {};
#pragma unroll 4
    for (int k0 = 0; k0 < H_; k0 += 32) {
        int koff = k0 + lg * 8;
        f32x4 w0 = *(const f32x4*)(wrow + koff);
        f32x4 w1 = *(const f32x4*)(wrow + koff + 4);
        bf16x8 bf = pack_bf16(w0, w1);
#pragma unroll
        for (int mf = 0; mf < 4; ++mf) {
            bf16x8 af = *(const bf16x8*)(midb + (size_t)(mf * 16 + lr) * H_ + koff);
            acc[mf] = __builtin_amdgcn_mfma_f32_16x16x32_bf16(af, bf, acc[mf], 0, 0, 0);
        }
    }
    float bias = valid ? bv[col] : 0.f;
    __shared__ float wsum[4][64];
#pragma unroll
    for (int mf = 0; mf < 4; ++mf) {
#pragma unroll
        for (int r = 0; r < 4; ++r) {
            int row = mf * 16 + lg * 4 + r;       // batch index
            float logit = acc[mf][r] + bias;
            logit = fminf(fmaxf(logit, -50.f), 50.f);
            float ev = valid ? __expf(logit - 50.f) : 0.f;
            if (valid) e[(size_t)row * VP + col] = ev;
            float s = ev;
            s += __shfl_xor(s, 1); s += __shfl_xor(s, 2);
            s += __shfl_xor(s, 4); s += __shfl_xor(s, 8);
            if (lr == 0) wsum[wave][row] = s;
        }
    }
    __syncthreads();
    if (threadIdx.x < 64) {
        int row = threadIdx.x;
        float t = wsum[0][row] + wsum[1][row] + wsum[2][row] + wsum[3][row];
        psum[(size_t)row * PSTR + blk] = t;
    }
}

// ---------------- Z reduction: zinv[b] = 1 / sum_blk psum ------------------
__global__ __launch_bounds__(256) void k_zred(const float* __restrict__ psum,
                                              float* __restrict__ zinv) {
    int b = blockIdx.x;
    int tid = threadIdx.x;
    float s = 0.f;
    for (int i = tid; i < NBLK; i += 256) s += psum[(size_t)b * PSTR + i];
#pragma unroll
    for (int m = 32; m >= 1; m >>= 1) s += __shfl_xor(s, m);
    __shared__ float r[4];
    int wave = tid >> 6, lane = tid & 63;
    if (lane == 0) r[wave] = s;
    __syncthreads();
    if (tid == 0) zinv[b] = 1.f / (r[0] + r[1] + r[2] + r[3]);
}

// ---------------- vocab_dist + generation part of final_dist ---------------
__global__ __launch_bounds__(256) void k_final(const float* __restrict__ e,
                                               const float* __restrict__ zinv,
                                               const float* __restrict__ pg,
                                               float* __restrict__ out0,
                                               float* __restrict__ out2) {
    int idx = blockIdx.x * 256 + threadIdx.x;     // < 64*50100
    if (idx >= B_ * EXTV) return;
    int b = idx / EXTV;
    int v = idx - b * EXTV;
    float o = 0.f;
    if (v < V_) {
        float vd = e[(size_t)b * VP + v] * zinv[b];
        out2[(size_t)b * V_ + v] = vd;
        o = pg[b] * vd;
    }
    out0[idx] = o;
}

// ---------------- copy-distribution scatter --------------------------------
__global__ __launch_bounds__(256) void k_scatter(const float* __restrict__ attn,
                                                 const int* __restrict__ sid,
                                                 const int* __restrict__ oov,
                                                 const float* __restrict__ pg,
                                                 float* __restrict__ out0) {
    int idx = blockIdx.x * 256 + threadIdx.x;
    if (idx >= B_ * S_) return;
    int b = idx / S_;
    int m = oov[idx];
    int tgt = (m >= 0) ? (V_ + m) : sid[idx];
    float w = (1.f - pg[b]) * attn[idx];
    atomicAdd(out0 + (size_t)b * EXTV + tgt, w);
}

extern "C" void kernel_launch(void* const* d_in, const int* in_sizes, int n_in,
                              void* d_out, int out_size, void* d_ws, size_t ws_size,
                              hipStream_t stream) {
    const float* dec  = (const float*)d_in[0];
    const float* ctx  = (const float*)d_in[1];
    const float* emb  = (const float*)d_in[2];
    const float* attn = (const float*)d_in[3];
    const int*   sid  = (const int*)d_in[4];
    const int*   oov  = (const int*)d_in[5];
    // d_in[6] = vocab_size (known statically = 50000)
    const float* Wm   = (const float*)d_in[7];
    const float* bm   = (const float*)d_in[8];
    const float* Wp   = (const float*)d_in[9];
    const float* bp   = (const float*)d_in[10];
    const float* Wv   = (const float*)d_in[11];
    const float* bv   = (const float*)d_in[12];

    float* out0 = (float*)d_out;                  // final_dist [64][50100]
    float* out1 = out0 + (size_t)B_ * EXTV;       // p_gen      [64]
    float* out2 = out1 + B_;                      // vocab_dist [64][50000]

    float*  e    = (float*)d_ws;                  // [64][VP]
    float*  psum = e + (size_t)B_ * VP;           // [64][PSTR]
    float*  zinv = psum + (size_t)B_ * PSTR;      // [64]
    float*  pg   = zinv + 64;                     // [64]
    float*  pmid = pg + 64;                       // [8][64][1024]
    __bf16* midb = (__bf16*)(pmid + (size_t)8 * B_ * H_); // [64][1024]

    k_pgen<<<B_, 256, 0, stream>>>(dec, ctx, emb, Wp, bp, pg, out1);
    dim3 gmid(16, 8);
    k_gemm_mid<<<gmid, 256, 0, stream>>>(dec, ctx, Wm, pmid);
    k_mid_reduce<<<(B_ * H_) / 256, 256, 0, stream>>>(pmid, bm, midb);
    k_gemm_vocab<<<NBLK, 256, 0, stream>>>(midb, Wv, bv, e, psum);
    k_zred<<<B_, 256, 0, stream>>>(psum, zinv);
    k_final<<<(B_ * EXTV + 255) / 256, 256, 0, stream>>>(e, zinv, pg, out0, out2);
    k_scatter<<<(B_ * S_ + 255) / 256, 256, 0, stream>>>(attn, sid, oov, pg, out0);
}

// Round 2
// 124.705 us; speedup vs baseline: 1.0277x; 1.0277x over previous
//
#include <hip/hip_runtime.h>
#include <hip/hip_bf16.h>

#define B_   64
#define H_   1024
#define E_   512
#define V_   50000
#define S_   400
#define EXTV 50100        // V + 100
#define K2   2048         // 2H
#define KP   2560         // 2H + E
#define VP   50016        // padded e row stride (multiple of 16)
#define NBLK 782          // ceil(V / 64)
#define PSTR 800          // padded partial-sum stride
#define KCH  16           // split-K chunks for mid GEMM

typedef float  f32x4  __attribute__((ext_vector_type(4)));
typedef __bf16 bf16x8 __attribute__((ext_vector_type(8)));

static __device__ __forceinline__ bf16x8 pack_bf16(f32x4 a, f32x4 b) {
    bf16x8 r;
    r[0] = (__bf16)a[0]; r[1] = (__bf16)a[1]; r[2] = (__bf16)a[2]; r[3] = (__bf16)a[3];
    r[4] = (__bf16)b[0]; r[5] = (__bf16)b[1]; r[6] = (__bf16)b[2]; r[7] = (__bf16)b[3];
    return r;
}

// ---------------- p_gen: 64 dots of length 2560 -----------------------------
__global__ __launch_bounds__(256) void k_pgen(const float* __restrict__ dec,
                                              const float* __restrict__ ctx,
                                              const float* __restrict__ emb,
                                              const float* __restrict__ Wp,
                                              const float* __restrict__ bp,
                                              float* __restrict__ pg,
                                              float* __restrict__ out1) {
    int b = blockIdx.x;
    int tid = threadIdx.x;
    float s = 0.f;
    for (int k = tid; k < KP; k += 256) {
        float x;
        if (k < H_)          x = dec[b * H_ + k];
        else if (k < 2 * H_) x = ctx[b * H_ + k - H_];
        else                 x = emb[b * E_ + k - 2 * H_];
        s += x * Wp[k];
    }
#pragma unroll
    for (int m = 32; m >= 1; m >>= 1) s += __shfl_xor(s, m);
    __shared__ float r[4];
    int wave = tid >> 6, lane = tid & 63;
    if (lane == 0) r[wave] = s;
    __syncthreads();
    if (tid == 0) {
        float t = r[0] + r[1] + r[2] + r[3] + bp[0];
        float p = 1.f / (1.f + __expf(-t));
        pg[b]   = p;
        out1[b] = p;
    }
}

// ---------------- mid GEMM (split-K 16): M=64, N=1024, K=2048 ---------------
__global__ __launch_bounds__(256, 4) void k_gemm_mid(const float* __restrict__ dec,
                                                     const float* __restrict__ ctx,
                                                     const float* __restrict__ Wm,
                                                     float* __restrict__ pmid) {
    int nt   = blockIdx.x;             // 0..15  (h-tile of 64)
    int kc   = blockIdx.y;             // 0..15  (K-chunk of 128)
    int wave = threadIdx.x >> 6;
    int lane = threadIdx.x & 63;
    int lr   = lane & 15, lg = lane >> 4;
    int col  = nt * 64 + wave * 16 + lr;          // h index
    const float* xb   = (kc < 8) ? dec : ctx;
    int kbase         = (kc & 7) * 128;
    const float* wrow = Wm + (size_t)col * K2 + kc * 128 + lg * 8;
    const float* xrow = xb + (size_t)lr * H_ + kbase + lg * 8;

    // prefetch the whole W chunk (4 iters x 8 floats)
    f32x4 w0s[4], w1s[4];
#pragma unroll
    for (int p = 0; p < 4; ++p) {
        w0s[p] = *(const f32x4*)(wrow + p * 32);
        w1s[p] = *(const f32x4*)(wrow + p * 32 + 4);
    }
    f32x4 acc[4] = {};
#pragma unroll
    for (int i = 0; i < 4; ++i) {
        // issue all activation loads for this iter first
        f32x4 a0[4], a1[4];
#pragma unroll
        for (int mf = 0; mf < 4; ++mf) {
            const float* xp = xrow + (size_t)(mf * 16) * H_ + i * 32;
            a0[mf] = *(const f32x4*)xp;
            a1[mf] = *(const f32x4*)(xp + 4);
        }
        bf16x8 bf = pack_bf16(w0s[i], w1s[i]);
#pragma unroll
        for (int mf = 0; mf < 4; ++mf) {
            bf16x8 af = pack_bf16(a0[mf], a1[mf]);
            acc[mf] = __builtin_amdgcn_mfma_f32_16x16x32_bf16(af, bf, acc[mf], 0, 0, 0);
        }
    }
#pragma unroll
    for (int mf = 0; mf < 4; ++mf)
#pragma unroll
        for (int r = 0; r < 4; ++r) {
            int row = mf * 16 + lg * 4 + r;       // batch index
            pmid[((size_t)kc * B_ + row) * H_ + col] = acc[mf][r];
        }
}

// ---------------- reduce split-K partials, bias, tanh, -> bf16 --------------
__global__ __launch_bounds__(256) void k_mid_reduce(const float* __restrict__ pmid,
                                                    const float* __restrict__ bm,
                                                    __bf16* __restrict__ midb) {
    int idx = blockIdx.x * 256 + threadIdx.x;     // 65536
    int h = idx & (H_ - 1);
    int m = idx >> 10;
    float s = bm[h];
#pragma unroll
    for (int kc = 0; kc < KCH; ++kc) s += pmid[((size_t)kc * B_ + m) * H_ + h];
    midb[idx] = (__bf16)tanhf(s);
}

// ---------------- big GEMM: e = exp(clip(mid @ Wv^T + bv) - 50) -------------
// Software-pipelined: W (HBM) staged depth-4, midb (L2) staged depth-2.
__global__ __launch_bounds__(256, 4) void k_gemm_vocab(const __bf16* __restrict__ midb,
                                                       const float* __restrict__ Wv,
                                                       const float* __restrict__ bv,
                                                       float* __restrict__ e,
                                                       float* __restrict__ psum) {
    int blk  = blockIdx.x;
    int wave = threadIdx.x >> 6;
    int lane = threadIdx.x & 63;
    int lr   = lane & 15, lg = lane >> 4;
    int col  = blk * 64 + wave * 16 + lr;         // vocab index
    bool valid = col < V_;
    int colc = valid ? col : V_ - 1;
    const float*  wrow = Wv + (size_t)colc * H_ + lg * 8;
    const __bf16* mrow = midb + (size_t)lr * H_ + lg * 8;

    f32x4  w0s[4], w1s[4];
    bf16x8 afs[2][4];
#pragma unroll
    for (int p = 0; p < 4; ++p) {
        w0s[p] = *(const f32x4*)(wrow + p * 32);
        w1s[p] = *(const f32x4*)(wrow + p * 32 + 4);
    }
#pragma unroll
    for (int mf = 0; mf < 4; ++mf)
        afs[0][mf] = *(const bf16x8*)(mrow + (size_t)(mf * 16) * H_);

    f32x4 acc[4] = {};
#pragma unroll
    for (int i = 0; i < 32; ++i) {
        f32x4 cw0 = w0s[i & 3], cw1 = w1s[i & 3];
        if (i + 4 < 32) {                          // refill W slot (depth 4)
            w0s[i & 3] = *(const f32x4*)(wrow + (i + 4) * 32);
            w1s[i & 3] = *(const f32x4*)(wrow + (i + 4) * 32 + 4);
        }
        if (i + 1 < 32) {                          // prefetch midb (depth 2)
#pragma unroll
            for (int mf = 0; mf < 4; ++mf)
                afs[(i + 1) & 1][mf] =
                    *(const bf16x8*)(mrow + (i + 1) * 32 + (size_t)(mf * 16) * H_);
        }
        bf16x8 bf = pack_bf16(cw0, cw1);
#pragma unroll
        for (int mf = 0; mf < 4; ++mf)
            acc[mf] = __builtin_amdgcn_mfma_f32_16x16x32_bf16(afs[i & 1][mf], bf, acc[mf], 0, 0, 0);
    }

    float bias = valid ? bv[col] : 0.f;
    __shared__ float wsum[4][64];
#pragma unroll
    for (int mf = 0; mf < 4; ++mf) {
#pragma unroll
        for (int r = 0; r < 4; ++r) {
            int row = mf * 16 + lg * 4 + r;       // batch index
            float logit = acc[mf][r] + bias;
            logit = fminf(fmaxf(logit, -50.f), 50.f);
            float ev = valid ? __expf(logit - 50.f) : 0.f;
            if (valid) e[(size_t)row * VP + col] = ev;
            float s = ev;
            s += __shfl_xor(s, 1); s += __shfl_xor(s, 2);
            s += __shfl_xor(s, 4); s += __shfl_xor(s, 8);
            if (lr == 0) wsum[wave][row] = s;
        }
    }
    __syncthreads();
    if (threadIdx.x < 64) {
        int row = threadIdx.x;
        float t = wsum[0][row] + wsum[1][row] + wsum[2][row] + wsum[3][row];
        psum[(size_t)row * PSTR + blk] = t;
    }
}

// ---------------- Z reduction: zinv[b] = 1 / sum_blk psum ------------------
__global__ __launch_bounds__(256) void k_zred(const float* __restrict__ psum,
                                              float* __restrict__ zinv) {
    int b = blockIdx.x;
    int tid = threadIdx.x;
    float s = 0.f;
    for (int i = tid; i < NBLK; i += 256) s += psum[(size_t)b * PSTR + i];
#pragma unroll
    for (int m = 32; m >= 1; m >>= 1) s += __shfl_xor(s, m);
    __shared__ float r[4];
    int wave = tid >> 6, lane = tid & 63;
    if (lane == 0) r[wave] = s;
    __syncthreads();
    if (tid == 0) zinv[b] = 1.f / (r[0] + r[1] + r[2] + r[3]);
}

// ---------------- vocab_dist + generation part of final_dist ---------------
__global__ __launch_bounds__(256) void k_final(const float* __restrict__ e,
                                               const float* __restrict__ zinv,
                                               const float* __restrict__ pg,
                                               float* __restrict__ out0,
                                               float* __restrict__ out2) {
    int idx = blockIdx.x * 256 + threadIdx.x;     // < 64*50100
    if (idx >= B_ * EXTV) return;
    int b = idx / EXTV;
    int v = idx - b * EXTV;
    float o = 0.f;
    if (v < V_) {
        float vd = e[(size_t)b * VP + v] * zinv[b];
        out2[(size_t)b * V_ + v] = vd;
        o = pg[b] * vd;
    }
    out0[idx] = o;
}

// ---------------- copy-distribution scatter --------------------------------
__global__ __launch_bounds__(256) void k_scatter(const float* __restrict__ attn,
                                                 const int* __restrict__ sid,
                                                 const int* __restrict__ oov,
                                                 const float* __restrict__ pg,
                                                 float* __restrict__ out0) {
    int idx = blockIdx.x * 256 + threadIdx.x;
    if (idx >= B_ * S_) return;
    int b = idx / S_;
    int m = oov[idx];
    int tgt = (m >= 0) ? (V_ + m) : sid[idx];
    float w = (1.f - pg[b]) * attn[idx];
    atomicAdd(out0 + (size_t)b * EXTV + tgt, w);
}

extern "C" void kernel_launch(void* const* d_in, const int* in_sizes, int n_in,
                              void* d_out, int out_size, void* d_ws, size_t ws_size,
                              hipStream_t stream) {
    const float* dec  = (const float*)d_in[0];
    const float* ctx  = (const float*)d_in[1];
    const float* emb  = (const float*)d_in[2];
    const float* attn = (const float*)d_in[3];
    const int*   sid  = (const int*)d_in[4];
    const int*   oov  = (const int*)d_in[5];
    // d_in[6] = vocab_size (known statically = 50000)
    const float* Wm   = (const float*)d_in[7];
    const float* bm   = (const float*)d_in[8];
    const float* Wp   = (const float*)d_in[9];
    const float* bp   = (const float*)d_in[10];
    const float* Wv   = (const float*)d_in[11];
    const float* bv   = (const float*)d_in[12];

    float* out0 = (float*)d_out;                  // final_dist [64][50100]
    float* out1 = out0 + (size_t)B_ * EXTV;       // p_gen      [64]
    float* out2 = out1 + B_;                      // vocab_dist [64][50000]

    float*  e    = (float*)d_ws;                  // [64][VP]
    float*  psum = e + (size_t)B_ * VP;           // [64][PSTR]
    float*  zinv = psum + (size_t)B_ * PSTR;      // [64]
    float*  pg   = zinv + 64;                     // [64]
    float*  pmid = pg + 64;                       // [KCH][64][1024]
    __bf16* midb = (__bf16*)(pmid + (size_t)KCH * B_ * H_); // [64][1024]

    k_pgen<<<B_, 256, 0, stream>>>(dec, ctx, emb, Wp, bp, pg, out1);
    dim3 gmid(16, KCH);
    k_gemm_mid<<<gmid, 256, 0, stream>>>(dec, ctx, Wm, pmid);
    k_mid_reduce<<<(B_ * H_) / 256, 256, 0, stream>>>(pmid, bm, midb);
    k_gemm_vocab<<<NBLK, 256, 0, stream>>>(midb, Wv, bv, e, psum);
    k_zred<<<B_, 256, 0, stream>>>(psum, zinv);
    k_final<<<(B_ * EXTV + 255) / 256, 256, 0, stream>>>(e, zinv, pg, out0, out2);
    k_scatter<<<(B_ * S_ + 255) / 256, 256, 0, stream>>>(attn, sid, oov, pg, out0);
}

// Round 3
// 84.882 us; speedup vs baseline: 1.5099x; 1.4692x over previous
//
#include <hip/hip_runtime.h>
#include <hip/hip_bf16.h>

#define B_   64
#define H_   1024
#define E_   512
#define V_   50000
#define S_   400
#define EXTV 50100        // V + 100
#define K2   2048         // 2H
#define KP   2560         // 2H + E
#define VP   50016        // padded e row stride (multiple of 16)
#define NBLK 782          // ceil(V / 64)
#define PSTR 800          // padded partial-sum stride
#define KCH  16           // split-K chunks for mid GEMM
#define WSL  8192         // W LDS slice bytes (64 cols x 32 f32)
#define ASL  4096         // A LDS slice bytes (64 rows x 32 bf16)

typedef float  f32x4  __attribute__((ext_vector_type(4)));
typedef __bf16 bf16x8 __attribute__((ext_vector_type(8)));

typedef __attribute__((address_space(1))) const void gas_t;
typedef __attribute__((address_space(3))) void las_t;
#define GLL16(g, l) __builtin_amdgcn_global_load_lds((gas_t*)(g), (las_t*)(l), 16, 0, 0)

static __device__ __forceinline__ bf16x8 pack_bf16(f32x4 a, f32x4 b) {
    bf16x8 r;
    r[0] = (__bf16)a[0]; r[1] = (__bf16)a[1]; r[2] = (__bf16)a[2]; r[3] = (__bf16)a[3];
    r[4] = (__bf16)b[0]; r[5] = (__bf16)b[1]; r[6] = (__bf16)b[2]; r[7] = (__bf16)b[3];
    return r;
}

// ---------------- p_gen: 64 dots of length 2560 -----------------------------
__global__ __launch_bounds__(256) void k_pgen(const float* __restrict__ dec,
                                              const float* __restrict__ ctx,
                                              const float* __restrict__ emb,
                                              const float* __restrict__ Wp,
                                              const float* __restrict__ bp,
                                              float* __restrict__ pg,
                                              float* __restrict__ out1) {
    int b = blockIdx.x;
    int tid = threadIdx.x;
    float s = 0.f;
    for (int k = tid; k < KP; k += 256) {
        float x;
        if (k < H_)          x = dec[b * H_ + k];
        else if (k < 2 * H_) x = ctx[b * H_ + k - H_];
        else                 x = emb[b * E_ + k - 2 * H_];
        s += x * Wp[k];
    }
#pragma unroll
    for (int m = 32; m >= 1; m >>= 1) s += __shfl_xor(s, m);
    __shared__ float r[4];
    int wave = tid >> 6, lane = tid & 63;
    if (lane == 0) r[wave] = s;
    __syncthreads();
    if (tid == 0) {
        float t = r[0] + r[1] + r[2] + r[3] + bp[0];
        float p = 1.f / (1.f + __expf(-t));
        pg[b]   = p;
        out1[b] = p;
    }
}

// ---------------- mid GEMM (split-K 16): M=64, N=1024, K=2048 ---------------
__global__ __launch_bounds__(256, 4) void k_gemm_mid(const float* __restrict__ dec,
                                                     const float* __restrict__ ctx,
                                                     const float* __restrict__ Wm,
                                                     float* __restrict__ pmid) {
    int nt   = blockIdx.x;             // 0..15  (h-tile of 64)
    int kc   = blockIdx.y;             // 0..15  (K-chunk of 128)
    int wave = threadIdx.x >> 6;
    int lane = threadIdx.x & 63;
    int lr   = lane & 15, lg = lane >> 4;
    int col  = nt * 64 + wave * 16 + lr;          // h index
    const float* xb   = (kc < 8) ? dec : ctx;
    int kbase         = (kc & 7) * 128;
    const float* wrow = Wm + (size_t)col * K2 + kc * 128 + lg * 8;
    const float* xrow = xb + (size_t)lr * H_ + kbase + lg * 8;

    f32x4 w0s[4], w1s[4];
#pragma unroll
    for (int p = 0; p < 4; ++p) {
        w0s[p] = *(const f32x4*)(wrow + p * 32);
        w1s[p] = *(const f32x4*)(wrow + p * 32 + 4);
    }
    f32x4 acc[4] = {};
#pragma unroll
    for (int i = 0; i < 4; ++i) {
        f32x4 a0[4], a1[4];
#pragma unroll
        for (int mf = 0; mf < 4; ++mf) {
            const float* xp = xrow + (size_t)(mf * 16) * H_ + i * 32;
            a0[mf] = *(const f32x4*)xp;
            a1[mf] = *(const f32x4*)(xp + 4);
        }
        bf16x8 bf = pack_bf16(w0s[i], w1s[i]);
#pragma unroll
        for (int mf = 0; mf < 4; ++mf) {
            bf16x8 af = pack_bf16(a0[mf], a1[mf]);
            acc[mf] = __builtin_amdgcn_mfma_f32_16x16x32_bf16(af, bf, acc[mf], 0, 0, 0);
        }
    }
#pragma unroll
    for (int mf = 0; mf < 4; ++mf)
#pragma unroll
        for (int r = 0; r < 4; ++r) {
            int row = mf * 16 + lg * 4 + r;       // batch index
            pmid[((size_t)kc * B_ + row) * H_ + col] = acc[mf][r];
        }
}

// ---------------- reduce split-K partials, bias, tanh, -> bf16 --------------
__global__ __launch_bounds__(256) void k_mid_reduce(const float* __restrict__ pmid,
                                                    const float* __restrict__ bm,
                                                    __bf16* __restrict__ midb) {
    int idx = blockIdx.x * 256 + threadIdx.x;     // 65536
    int h = idx & (H_ - 1);
    int m = idx >> 10;
    float s = bm[h];
#pragma unroll
    for (int kc = 0; kc < KCH; ++kc) s += pmid[((size_t)kc * B_ + m) * H_ + h];
    midb[idx] = (__bf16)tanhf(s);
}

// ---------------- big GEMM: e = exp(clip(mid @ Wv^T + bv) - 50) -------------
// global_load_lds DMA pipeline, depth 4, counted vmcnt, raw s_barrier.
// W LDS layout: byte col*128 + (t ^ (col&7))*16 holds Wv[col][k0 + t*4 .. +4]
// A LDS layout: byte row*64  + (s ^ ((row>>1)&3))*16 holds midb[row][k0 + s*8 .. +8]
__global__ __launch_bounds__(256, 3) void k_gemm_vocab(const __bf16* __restrict__ midb,
                                                       const float* __restrict__ Wv,
                                                       const float* __restrict__ bv,
                                                       float* __restrict__ e,
                                                       float* __restrict__ psum) {
    __shared__ __align__(16) char ldsW[4 * WSL];   // 32 KB
    __shared__ __align__(16) char ldsA[4 * ASL];   // 16 KB
    int tid  = threadIdx.x;
    int wave = tid >> 6;
    int lane = tid & 63;
    int lr   = lane & 15, lg = lane >> 4;
    int blk  = blockIdx.x;
    int colBase = blk * 64;

    // ---- staging source addresses (per-lane, pre-swizzled: rule #21) ----
    int c1 = colBase + wave * 8 + (lane >> 3);         // W chunk a: cols 0..31
    int c2 = c1 + 32;                                  // W chunk b: cols 32..63
    if (c1 >= V_) c1 = V_ - 1;
    if (c2 >= V_) c2 = V_ - 1;
    int tsw = (((lane & 7) ^ (lane >> 3)) << 4);       // (t ^ (col&7))*16 bytes
    const char* srcW1 = (const char*)Wv + (size_t)c1 * 4096 + tsw;
    const char* srcW2 = (const char*)Wv + (size_t)c2 * 4096 + tsw;
    int arow = wave * 16 + (lane >> 2);                // A: row per lane
    int asw  = (((lane & 3) ^ ((lane >> 3) & 3)) << 4);// (s ^ phi(row))*16 bytes
    const char* srcA = (const char*)midb + (size_t)arow * 2048 + asw;

    // ---- LDS destinations (wave-uniform base; DMA writes base+lane*16) ----
    char* dW1 = ldsW + wave * 1024;
    char* dW2 = ldsW + 4096 + wave * 1024;
    char* dA  = ldsA + wave * 1024;

    // ---- LDS read offsets (swizzled) ----
    int col    = wave * 16 + lr;                       // block-local vocab col
    int w_off0 = col * 128 + ((((lg * 2)     ) ^ (lr & 7)) << 4);
    int w_off1 = col * 128 + ((((lg * 2) + 1 ) ^ (lr & 7)) << 4);
    int phiA   = (lr >> 1) & 3;
    int aoff0  = (0 * 16 + lr) * 64 + ((lg ^ phiA) << 4);
    int aoff1  = (1 * 16 + lr) * 64 + ((lg ^ phiA) << 4);
    int aoff2  = (2 * 16 + lr) * 64 + ((lg ^ phiA) << 4);
    int aoff3  = (3 * 16 + lr) * 64 + ((lg ^ phiA) << 4);

    f32x4 acc0 = {}, acc1 = {}, acc2 = {}, acc3 = {};

    // ---- prologue: stage slices 0,1,2 (3 DMA instrs per slice per wave) ----
#pragma unroll
    for (int s = 0; s < 3; ++s) {
        GLL16(srcW1 + s * 128, dW1 + s * WSL);
        GLL16(srcW2 + s * 128, dW2 + s * WSL);
        GLL16(srcA  + s * 64,  dA  + s * ASL);
    }

#define VBODY(i, N) do {                                                        \
        __builtin_amdgcn_sched_barrier(0);                                      \
        asm volatile("s_waitcnt vmcnt(" #N ")" ::: "memory");                   \
        __builtin_amdgcn_s_barrier();                                           \
        if ((i) + 3 < 32) {                                                     \
            GLL16(srcW1 + ((i) + 3) * 128, dW1 + (((i) + 3) & 3) * WSL);        \
            GLL16(srcW2 + ((i) + 3) * 128, dW2 + (((i) + 3) & 3) * WSL);        \
            GLL16(srcA  + ((i) + 3) * 64,  dA  + (((i) + 3) & 3) * ASL);        \
        }                                                                       \
        const char* wS = ldsW + ((i) & 3) * WSL;                                \
        const char* aS = ldsA + ((i) & 3) * ASL;                                \
        f32x4 w0 = *(const f32x4*)(wS + w_off0);                                \
        f32x4 w1 = *(const f32x4*)(wS + w_off1);                                \
        bf16x8 bfr = pack_bf16(w0, w1);                                         \
        bf16x8 af0 = *(const bf16x8*)(aS + aoff0);                              \
        bf16x8 af1 = *(const bf16x8*)(aS + aoff1);                              \
        bf16x8 af2 = *(const bf16x8*)(aS + aoff2);                              \
        bf16x8 af3 = *(const bf16x8*)(aS + aoff3);                              \
        acc0 = __builtin_amdgcn_mfma_f32_16x16x32_bf16(af0, bfr, acc0, 0, 0, 0);\
        acc1 = __builtin_amdgcn_mfma_f32_16x16x32_bf16(af1, bfr, acc1, 0, 0, 0);\
        acc2 = __builtin_amdgcn_mfma_f32_16x16x32_bf16(af2, bfr, acc2, 0, 0, 0);\
        acc3 = __builtin_amdgcn_mfma_f32_16x16x32_bf16(af3, bfr, acc3, 0, 0, 0);\
    } while (0)

    VBODY(0, 6);  VBODY(1, 6);  VBODY(2, 6);  VBODY(3, 6);
    VBODY(4, 6);  VBODY(5, 6);  VBODY(6, 6);  VBODY(7, 6);
    VBODY(8, 6);  VBODY(9, 6);  VBODY(10, 6); VBODY(11, 6);
    VBODY(12, 6); VBODY(13, 6); VBODY(14, 6); VBODY(15, 6);
    VBODY(16, 6); VBODY(17, 6); VBODY(18, 6); VBODY(19, 6);
    VBODY(20, 6); VBODY(21, 6); VBODY(22, 6); VBODY(23, 6);
    VBODY(24, 6); VBODY(25, 6); VBODY(26, 6); VBODY(27, 6);
    VBODY(28, 6); VBODY(29, 6); VBODY(30, 3); VBODY(31, 0);
#undef VBODY

    int gcol = colBase + col;
    bool valid = gcol < V_;
    float bias = valid ? bv[valid ? gcol : V_ - 1] : 0.f;
    __shared__ float wsum[4][64];
    f32x4 accs[4] = {acc0, acc1, acc2, acc3};
#pragma unroll
    for (int mf = 0; mf < 4; ++mf) {
#pragma unroll
        for (int r = 0; r < 4; ++r) {
            int row = mf * 16 + lg * 4 + r;       // batch index
            float logit = accs[mf][r] + bias;
            logit = fminf(fmaxf(logit, -50.f), 50.f);
            float ev = valid ? __expf(logit - 50.f) : 0.f;
            if (valid) e[(size_t)row * VP + gcol] = ev;
            float s = ev;
            s += __shfl_xor(s, 1); s += __shfl_xor(s, 2);
            s += __shfl_xor(s, 4); s += __shfl_xor(s, 8);
            if (lr == 0) wsum[wave][row] = s;
        }
    }
    __syncthreads();
    if (threadIdx.x < 64) {
        int row = threadIdx.x;
        float t = wsum[0][row] + wsum[1][row] + wsum[2][row] + wsum[3][row];
        psum[(size_t)row * PSTR + blk] = t;
    }
}

// ---------------- Z reduction: zinv[b] = 1 / sum_blk psum ------------------
__global__ __launch_bounds__(256) void k_zred(const float* __restrict__ psum,
                                              float* __restrict__ zinv) {
    int b = blockIdx.x;
    int tid = threadIdx.x;
    float s = 0.f;
    for (int i = tid; i < NBLK; i += 256) s += psum[(size_t)b * PSTR + i];
#pragma unroll
    for (int m = 32; m >= 1; m >>= 1) s += __shfl_xor(s, m);
    __shared__ float r[4];
    int wave = tid >> 6, lane = tid & 63;
    if (lane == 0) r[wave] = s;
    __syncthreads();
    if (tid == 0) zinv[b] = 1.f / (r[0] + r[1] + r[2] + r[3]);
}

// ---------------- vocab_dist + generation part of final_dist ---------------
__global__ __launch_bounds__(256) void k_final(const float* __restrict__ e,
                                               const float* __restrict__ zinv,
                                               const float* __restrict__ pg,
                                               float* __restrict__ out0,
                                               float* __restrict__ out2) {
    int idx = blockIdx.x * 256 + threadIdx.x;     // < 64*50100
    if (idx >= B_ * EXTV) return;
    int b = idx / EXTV;
    int v = idx - b * EXTV;
    float o = 0.f;
    if (v < V_) {
        float vd = e[(size_t)b * VP + v] * zinv[b];
        out2[(size_t)b * V_ + v] = vd;
        o = pg[b] * vd;
    }
    out0[idx] = o;
}

// ---------------- copy-distribution scatter --------------------------------
__global__ __launch_bounds__(256) void k_scatter(const float* __restrict__ attn,
                                                 const int* __restrict__ sid,
                                                 const int* __restrict__ oov,
                                                 const float* __restrict__ pg,
                                                 float* __restrict__ out0) {
    int idx = blockIdx.x * 256 + threadIdx.x;
    if (idx >= B_ * S_) return;
    int b = idx / S_;
    int m = oov[idx];
    int tgt = (m >= 0) ? (V_ + m) : sid[idx];
    float w = (1.f - pg[b]) * attn[idx];
    atomicAdd(out0 + (size_t)b * EXTV + tgt, w);
}

extern "C" void kernel_launch(void* const* d_in, const int* in_sizes, int n_in,
                              void* d_out, int out_size, void* d_ws, size_t ws_size,
                              hipStream_t stream) {
    const float* dec  = (const float*)d_in[0];
    const float* ctx  = (const float*)d_in[1];
    const float* emb  = (const float*)d_in[2];
    const float* attn = (const float*)d_in[3];
    const int*   sid  = (const int*)d_in[4];
    const int*   oov  = (const int*)d_in[5];
    // d_in[6] = vocab_size (known statically = 50000)
    const float* Wm   = (const float*)d_in[7];
    const float* bm   = (const float*)d_in[8];
    const float* Wp   = (const float*)d_in[9];
    const float* bp   = (const float*)d_in[10];
    const float* Wv   = (const float*)d_in[11];
    const float* bv   = (const float*)d_in[12];

    float* out0 = (float*)d_out;                  // final_dist [64][50100]
    float* out1 = out0 + (size_t)B_ * EXTV;       // p_gen      [64]
    float* out2 = out1 + B_;                      // vocab_dist [64][50000]

    float*  e    = (float*)d_ws;                  // [64][VP]
    float*  psum = e + (size_t)B_ * VP;           // [64][PSTR]
    float*  zinv = psum + (size_t)B_ * PSTR;      // [64]
    float*  pg   = zinv + 64;                     // [64]
    float*  pmid = pg + 64;                       // [KCH][64][1024]
    __bf16* midb = (__bf16*)(pmid + (size_t)KCH * B_ * H_); // [64][1024]

    k_pgen<<<B_, 256, 0, stream>>>(dec, ctx, emb, Wp, bp, pg, out1);
    dim3 gmid(16, KCH);
    k_gemm_mid<<<gmid, 256, 0, stream>>>(dec, ctx, Wm, pmid);
    k_mid_reduce<<<(B_ * H_) / 256, 256, 0, stream>>>(pmid, bm, midb);
    k_gemm_vocab<<<NBLK, 256, 0, stream>>>((const __bf16*)midb, Wv, bv, e, psum);
    k_zred<<<B_, 256, 0, stream>>>(psum, zinv);
    k_final<<<(B_ * EXTV + 255) / 256, 256, 0, stream>>>(e, zinv, pg, out0, out2);
    k_scatter<<<(B_ * S_ + 255) / 256, 256, 0, stream>>>(attn, sid, oov, pg, out0);
}